// Round 8
// baseline (266.860 us; speedup 1.0000x reference)
//
#include <hip/hip_runtime.h>
#include <math.h>

#define NN 864
#define INF_ 4096
#define OUTF 1024
#define ALPHA 0.2f
#define NEGINF -9e15f
#define KSPLIT1 8

typedef short bf16x8 __attribute__((ext_vector_type(8)));
typedef float f32x4 __attribute__((ext_vector_type(4)));
typedef unsigned short u16x8 __attribute__((ext_vector_type(8)));
typedef unsigned short u16x4 __attribute__((ext_vector_type(4)));

__device__ __forceinline__ unsigned short f2bf(float f) {  // round-to-nearest-even
    unsigned int u = __float_as_uint(f);
    unsigned int r = (u + 0x7fffu + ((u >> 16) & 1u)) >> 16;
    return (unsigned short)r;
}
__device__ __forceinline__ float bf2f(unsigned short u) {
    return __uint_as_float((unsigned int)u << 16);
}

// ---------- block-wide reduction of two values (256 threads = 4 waves) ----------
__device__ __forceinline__ float2 blockReduce2(float v1, float v2, bool is_max) {
    __shared__ float r1[4], r2[4];
    const int lane = threadIdx.x & 63;
    const int wid  = threadIdx.x >> 6;
#pragma unroll
    for (int o = 32; o; o >>= 1) {
        float o1 = __shfl_down(v1, o, 64);
        float o2 = __shfl_down(v2, o, 64);
        if (is_max) { v1 = fmaxf(v1, o1); v2 = fmaxf(v2, o2); }
        else        { v1 += o1;           v2 += o2; }
    }
    __syncthreads();
    if (lane == 0) { r1[wid] = v1; r2[wid] = v2; }
    __syncthreads();
    float a = r1[0], b = r2[0];
#pragma unroll
    for (int w = 1; w < 4; ++w) {
        if (is_max) { a = fmaxf(a, r1[w]); b = fmaxf(b, r2[w]); }
        else        { a += r1[w];          b += r2[w]; }
    }
    return make_float2(a, b);
}

// ---------- prepW: W->W^T bf16 | Wa1/Wa2 fp32 | zero the attn counter ----------
__global__ __launch_bounds__(256) void prepW_kernel(
        const float* __restrict__ W, const float* __restrict__ a,
        unsigned short* __restrict__ wtbf, float* __restrict__ wa1,
        float* __restrict__ wa2, unsigned int* __restrict__ counter) {
    const int b = blockIdx.x;
    if (b < 2048) {                          // W^T bf16
        const int n  = (b & 3) * 256 + threadIdx.x;
        const int k0 = (b >> 2) * 8;
        u16x8 o;
#pragma unroll
        for (int j = 0; j < 8; ++j) o[j] = f2bf(W[(size_t)(k0 + j) * OUTF + n]);
        *(u16x8*)(wtbf + (size_t)n * INF_ + k0) = o;
    } else {                                 // Wa (fp32 exact logits path), 1 k-row per wave
        if (b == 2048 && threadIdx.x == 0) *counter = 0u;
        const int wid  = threadIdx.x >> 6;
        const int lane = threadIdx.x & 63;
        const int k = (b - 2048) * 4 + wid;
        const float* row = W + (size_t)k * OUTF;
        float s1 = 0.f, s2 = 0.f;
#pragma unroll
        for (int f = lane * 4; f < OUTF; f += 256) {
            float4 w = *(const float4*)(row + f);
            float4 x = *(const float4*)(a + f);
            float4 y = *(const float4*)(a + OUTF + f);
            s1 += w.x * x.x + w.y * x.y + w.z * x.z + w.w * x.w;
            s2 += w.x * y.x + w.y * y.y + w.z * y.z + w.w * y.w;
        }
#pragma unroll
        for (int o = 32; o; o >>= 1) { s1 += __shfl_down(s1, o, 64); s2 += __shfl_down(s2, o, 64); }
        if (lane == 0) { wa1[k] = s1; wa2[k] = s2; }
    }
}

// ---------- prepH: h->bf16 (rows 864..895 zeroed) fused with Wh1/Wh2 dots ----------
__global__ __launch_bounds__(256) void prepH_kernel(
        const float* __restrict__ h, const float* __restrict__ wa1,
        const float* __restrict__ wa2, unsigned short* __restrict__ hbf,
        float* __restrict__ wh1, float* __restrict__ wh2) {
    const int i = blockIdx.x;
    const int f = threadIdx.x * 16;
    if (i >= NN) {                            // zero pad rows for MFMA tiles
        u16x8 z;
#pragma unroll
        for (int j = 0; j < 8; ++j) z[j] = 0;
        *(u16x8*)(hbf + (size_t)i * INF_ + f)     = z;
        *(u16x8*)(hbf + (size_t)i * INF_ + f + 8) = z;
        return;
    }
    const float* row = h + (size_t)i * INF_;
    float4 f0 = *(const float4*)(row + f);
    float4 f1 = *(const float4*)(row + f + 4);
    float4 f2 = *(const float4*)(row + f + 8);
    float4 f3 = *(const float4*)(row + f + 12);
    u16x8 o0, o1;
    o0[0] = f2bf(f0.x); o0[1] = f2bf(f0.y); o0[2] = f2bf(f0.z); o0[3] = f2bf(f0.w);
    o0[4] = f2bf(f1.x); o0[5] = f2bf(f1.y); o0[6] = f2bf(f1.z); o0[7] = f2bf(f1.w);
    o1[0] = f2bf(f2.x); o1[1] = f2bf(f2.y); o1[2] = f2bf(f2.z); o1[3] = f2bf(f2.w);
    o1[4] = f2bf(f3.x); o1[5] = f2bf(f3.y); o1[6] = f2bf(f3.z); o1[7] = f2bf(f3.w);
    *(u16x8*)(hbf + (size_t)i * INF_ + f)     = o0;
    *(u16x8*)(hbf + (size_t)i * INF_ + f + 8) = o1;
    float4 x0 = *(const float4*)(wa1 + f),     x1 = *(const float4*)(wa1 + f + 4);
    float4 x2 = *(const float4*)(wa1 + f + 8), x3 = *(const float4*)(wa1 + f + 12);
    float4 y0 = *(const float4*)(wa2 + f),     y1 = *(const float4*)(wa2 + f + 4);
    float4 y2 = *(const float4*)(wa2 + f + 8), y3 = *(const float4*)(wa2 + f + 12);
    float s1 = f0.x * x0.x + f0.y * x0.y + f0.z * x0.z + f0.w * x0.w
             + f1.x * x1.x + f1.y * x1.y + f1.z * x1.z + f1.w * x1.w
             + f2.x * x2.x + f2.y * x2.y + f2.z * x2.z + f2.w * x2.w
             + f3.x * x3.x + f3.y * x3.y + f3.z * x3.z + f3.w * x3.w;
    float s2 = f0.x * y0.x + f0.y * y0.y + f0.z * y0.z + f0.w * y0.w
             + f1.x * y1.x + f1.y * y1.y + f1.z * y1.z + f1.w * y1.w
             + f2.x * y2.x + f2.y * y2.y + f2.z * y2.z + f2.w * y2.w
             + f3.x * y3.x + f3.y * y3.y + f3.z * y3.z + f3.w * y3.w;
    float2 s = blockReduce2(s1, s2, false);
    if (threadIdx.x == 0) { wh1[i] = s.x; wh2[i] = s.y; }
}

// ---------- GEMM1 (bf16 MFMA): P[z] = hbf @ wtbf^T, 128x128 tile, BK=32 ----------
__global__ __launch_bounds__(256) void gemm1_mfma_kernel(
        const unsigned short* __restrict__ Abf,   // [896][4096]
        const unsigned short* __restrict__ Btbf,  // [1024][4096]
        float* __restrict__ P, int kchunk) {
    __shared__ unsigned short Als[128][40];
    __shared__ unsigned short Bls[128][40];
    const int tid  = threadIdx.x;
    const int lane = tid & 63;
    const int wid  = tid >> 6;
    const int wr   = (wid >> 1) * 64;
    const int wc   = (wid & 1) * 64;
    const int brow = blockIdx.y * 128;
    const int bcol = blockIdx.x * 128;
    const int k0   = blockIdx.z * kchunk;
    const int r0   = tid >> 2;
    const int kq0  = (tid & 3) << 3;

    f32x4 acc[4][4];
#pragma unroll
    for (int m = 0; m < 4; ++m)
#pragma unroll
        for (int n = 0; n < 4; ++n) acc[m][n] = (f32x4){0.f, 0.f, 0.f, 0.f};

    const unsigned short* ag = Abf  + (size_t)(brow + r0) * INF_ + kq0;
    const unsigned short* bg = Btbf + (size_t)(bcol + r0) * INF_ + kq0;
    const int rl  = lane & 15;
    const int kq2 = (lane >> 4) << 3;

    for (int kk = k0; kk < k0 + kchunk; kk += 32) {
        bf16x8 a0 = *(const bf16x8*)(ag + kk);
        bf16x8 a1 = *(const bf16x8*)(ag + (size_t)64 * INF_ + kk);
        bf16x8 b0 = *(const bf16x8*)(bg + kk);
        bf16x8 b1 = *(const bf16x8*)(bg + (size_t)64 * INF_ + kk);
        __syncthreads();
        *(bf16x8*)&Als[r0][kq0]      = a0;
        *(bf16x8*)&Als[r0 + 64][kq0] = a1;
        *(bf16x8*)&Bls[r0][kq0]      = b0;
        *(bf16x8*)&Bls[r0 + 64][kq0] = b1;
        __syncthreads();
        bf16x8 af[4], bfr[4];
#pragma unroll
        for (int m = 0; m < 4; ++m) af[m]  = *(const bf16x8*)&Als[wr + m * 16 + rl][kq2];
#pragma unroll
        for (int n = 0; n < 4; ++n) bfr[n] = *(const bf16x8*)&Bls[wc + n * 16 + rl][kq2];
#pragma unroll
        for (int m = 0; m < 4; ++m)
#pragma unroll
            for (int n = 0; n < 4; ++n)
                acc[m][n] = __builtin_amdgcn_mfma_f32_16x16x32_bf16(af[m], bfr[n], acc[m][n], 0, 0, 0);
    }

    float* Pz = P + (size_t)blockIdx.z * NN * OUTF;
    const int rg = (lane >> 4) << 2;   // C/D: col=lane&15, row=(lane>>4)*4+reg (m89)
#pragma unroll
    for (int m = 0; m < 4; ++m) {
#pragma unroll
        for (int n = 0; n < 4; ++n) {
            const int row0 = brow + wr + m * 16 + rg;
            const int col  = bcol + wc + n * 16 + rl;
#pragma unroll
            for (int reg = 0; reg < 4; ++reg) {
                const int row = row0 + reg;
                if (row < NN) Pz[(size_t)row * OUTF + col] = acc[m][n][reg];
            }
        }
    }
}

// ---------- reduce 8 split-K partials -> Wh^T bf16 [1024][864], tiled LDS transpose ----------
__global__ __launch_bounds__(256) void reduce8t_kernel(const float* __restrict__ P,
                                                       unsigned short* __restrict__ Wt) {
    __shared__ unsigned short T[32][36];     // 36-stride: 2-way banks (free)
    const size_t stride = (size_t)NN * OUTF;
    const int m0 = (blockIdx.x >> 5) * 32;   // 27 row-tiles
    const int c0 = (blockIdx.x & 31) * 32;   // 32 col-tiles
    const int r  = threadIdx.x >> 3;
    const int c4 = (threadIdx.x & 7) << 2;
    const float* base = P + (size_t)(m0 + r) * OUTF + c0 + c4;
    float4 s = *(const float4*)base;
#pragma unroll
    for (int z = 1; z < KSPLIT1; ++z) {
        float4 v = *(const float4*)(base + (size_t)z * stride);
        s.x += v.x; s.y += v.y; s.z += v.z; s.w += v.w;
    }
    T[r][c4 + 0] = f2bf(s.x); T[r][c4 + 1] = f2bf(s.y);
    T[r][c4 + 2] = f2bf(s.z); T[r][c4 + 3] = f2bf(s.w);
    __syncthreads();
    const int c  = threadIdx.x >> 3;
    const int m8 = (threadIdx.x & 7) << 2;
    u16x4 o;
#pragma unroll
    for (int j = 0; j < 4; ++j) o[j] = T[m8 + j][c];
    *(u16x4*)(Wt + (size_t)(c0 + c) * NN + m0 + m8) = o;
}

// ---------- attn: masked softmaxes -> att bf16 + pool partials; last block -> wvec ----------
__global__ __launch_bounds__(256) void attn_kernel(
        const float* __restrict__ Wh1, const float* __restrict__ Wh2,
        const int* __restrict__ adj1, const int* __restrict__ adj2,
        unsigned short* __restrict__ att1, unsigned short* __restrict__ att2,
        float* __restrict__ rowpool, unsigned int* __restrict__ counter,
        const float* __restrict__ L_w, const float* __restrict__ L_b,
        float* __restrict__ wvec) {
    const int i = blockIdx.x, t = threadIdx.x;
    const int c = t * 4;
    const bool valid = c < NN;               // t < 216
    const float wh1i = Wh1[i];
    float l1[4], l2[4];
    float m1 = NEGINF, m2 = NEGINF;
    if (valid) {
        int4   av1 = *(const int4*)(adj1 + (size_t)i * NN + c);
        int4   av2 = *(const int4*)(adj2 + (size_t)i * NN + c);
        float4 w2  = *(const float4*)(Wh2 + c);
        float e;
        e = wh1i + w2.x; e = e > 0.f ? e : ALPHA * e;
        l1[0] = av1.x > 0 ? e : NEGINF; l2[0] = av2.x > 0 ? e : NEGINF;
        e = wh1i + w2.y; e = e > 0.f ? e : ALPHA * e;
        l1[1] = av1.y > 0 ? e : NEGINF; l2[1] = av2.y > 0 ? e : NEGINF;
        e = wh1i + w2.z; e = e > 0.f ? e : ALPHA * e;
        l1[2] = av1.z > 0 ? e : NEGINF; l2[2] = av2.z > 0 ? e : NEGINF;
        e = wh1i + w2.w; e = e > 0.f ? e : ALPHA * e;
        l1[3] = av1.w > 0 ? e : NEGINF; l2[3] = av2.w > 0 ? e : NEGINF;
#pragma unroll
        for (int j = 0; j < 4; ++j) { m1 = fmaxf(m1, l1[j]); m2 = fmaxf(m2, l2[j]); }
    } else {
#pragma unroll
        for (int j = 0; j < 4; ++j) { l1[j] = NEGINF; l2[j] = NEGINF; }
    }
    float2 m = blockReduce2(m1, m2, true);
    float x1[4], x2[4], s1 = 0.f, s2 = 0.f;
#pragma unroll
    for (int j = 0; j < 4; ++j) {
        x1[j] = valid ? expf(l1[j] - m.x) : 0.f;   // invalid lanes excluded from sum
        x2[j] = valid ? expf(l2[j] - m.y) : 0.f;
        s1 += x1[j]; s2 += x2[j];
    }
    float2 s = blockReduce2(s1, s2, false);
    const float inv1 = 1.f / s.x, inv2 = 1.f / s.y;
    float a1[4], a2[4];
    if (valid) {
        u16x4 o1, o2;
#pragma unroll
        for (int j = 0; j < 4; ++j) {
            a1[j] = x1[j] * inv1; o1[j] = f2bf(a1[j]);
            a2[j] = x2[j] * inv2; o2[j] = f2bf(a2[j]);
        }
        *(u16x4*)(att1 + (size_t)i * NN + c) = o1;
        *(u16x4*)(att2 + (size_t)i * NN + c) = o2;
    } else {
#pragma unroll
        for (int j = 0; j < 4; ++j) { a1[j] = NEGINF; a2[j] = NEGINF; }
    }
    float p1 = fmaxf(fmaxf(a1[0], a1[1]), fmaxf(a1[2], a1[3]));
    float p2 = fmaxf(fmaxf(a2[0], a2[1]), fmaxf(a2[2], a2[3]));
    p1 = fmaxf(p1, __shfl_xor(p1, 1, 64)); p1 = fmaxf(p1, __shfl_xor(p1, 2, 64));
    p2 = fmaxf(p2, __shfl_xor(p2, 1, 64)); p2 = fmaxf(p2, __shfl_xor(p2, 2, 64));
    if ((t & 3) == 0 && valid) {
        rowpool[(size_t)i * 54 + (t >> 2)] = p1;
        rowpool[(size_t)NN * 54 + (size_t)i * 54 + (t >> 2)] = p2;
    }

    // ---- last-block fusion of pool-finish + linear + leaky + softmax ----
    __shared__ unsigned int lastFlag;
    __threadfence();                          // publish rowpool (device scope)
    if (t == 0) lastFlag = (atomicAdd(counter, 1u) == NN - 1) ? 1u : 0u;
    __syncthreads();
    if (!lastFlag) return;
    __threadfence();                          // acquire other blocks' rowpool
    float q0 = 0.f, q1 = 0.f;
    for (int p = t; p < 2916; p += 256) {
        const int pi = p / 54, pj = p - pi * 54;
        const float* rp0 = rowpool + (size_t)(pi * 16) * 54 + pj;
        const float* rp1 = rp0 + (size_t)NN * 54;
        float mx0 = NEGINF, mx1 = NEGINF;
#pragma unroll
        for (int r = 0; r < 16; ++r) {
            mx0 = fmaxf(mx0, rp0[r * 54]);
            mx1 = fmaxf(mx1, rp1[r * 54]);
        }
        const float lw = L_w[p];
        q0 += mx0 * lw; q1 += mx1 * lw;
    }
    float2 sw = blockReduce2(q0, q1, false);
    if (t == 0) {
        float l0 = sw.x + L_b[0]; l0 = l0 > 0.f ? l0 : ALPHA * l0;
        float l1b = sw.y + L_b[0]; l1b = l1b > 0.f ? l1b : ALPHA * l1b;
        const float mx = fmaxf(l0, l1b);
        const float e0 = expf(l0 - mx), e1 = expf(l1b - mx);
        const float inv = 1.f / (e0 + e1);
        wvec[0] = e0 * inv; wvec[1] = e1 * inv;
    }
}

// ---------- GEMM2 (bf16 MFMA, single-K): out = ELU((w0*att1+w1*att2) @ Wh) ----------
__global__ __launch_bounds__(256) void gemm2_mfma_kernel(
        const unsigned short* __restrict__ A1, const unsigned short* __restrict__ A2,
        const float* __restrict__ wvec, const unsigned short* __restrict__ Bt,  // [1024][864]
        float* __restrict__ out) {
    __shared__ unsigned short Als[128][40];
    __shared__ unsigned short Bls[64][40];
    const int tid  = threadIdx.x;
    const int lane = tid & 63;
    const int wid  = tid >> 6;
    const int wr   = (wid >> 1) * 64;        // 2x2 waves of 64x32
    const int wc   = (wid & 1) * 32;
    const int brow = blockIdx.y * 128;
    const int bcol = blockIdx.x * 64;
    const int r0   = tid >> 2;
    const int kq0  = (tid & 3) << 3;
    const float w0 = wvec[0], w1 = wvec[1];

    f32x4 acc[4][2];
#pragma unroll
    for (int m = 0; m < 4; ++m)
#pragma unroll
        for (int n = 0; n < 2; ++n) acc[m][n] = (f32x4){0.f, 0.f, 0.f, 0.f};

    const int rl  = lane & 15;
    const int kq2 = (lane >> 4) << 3;

    for (int kk = 0; kk < NN; kk += 32) {    // 27 iters
        u16x8 av[2];
#pragma unroll
        for (int half = 0; half < 2; ++half) {
            const int grow = brow + r0 + half * 64;
            u16x8 o;
            if (grow < NN) {
                u16x8 v1 = *(const u16x8*)(A1 + (size_t)grow * NN + kk + kq0);
                u16x8 v2 = *(const u16x8*)(A2 + (size_t)grow * NN + kk + kq0);
#pragma unroll
                for (int j = 0; j < 8; ++j)
                    o[j] = f2bf(w0 * bf2f(v1[j]) + w1 * bf2f(v2[j]));
            } else {
#pragma unroll
                for (int j = 0; j < 8; ++j) o[j] = 0;
            }
            av[half] = o;
        }
        u16x8 bv = *(const u16x8*)(Bt + (size_t)(bcol + r0) * NN + kk + kq0);
        __syncthreads();
        *(u16x8*)&Als[r0][kq0]      = av[0];
        *(u16x8*)&Als[r0 + 64][kq0] = av[1];
        *(u16x8*)&Bls[r0][kq0]      = bv;
        __syncthreads();
        bf16x8 af[4], bfr[2];
#pragma unroll
        for (int m = 0; m < 4; ++m) af[m]  = *(const bf16x8*)&Als[wr + m * 16 + rl][kq2];
#pragma unroll
        for (int n = 0; n < 2; ++n) bfr[n] = *(const bf16x8*)&Bls[wc + n * 16 + rl][kq2];
#pragma unroll
        for (int m = 0; m < 4; ++m)
#pragma unroll
            for (int n = 0; n < 2; ++n)
                acc[m][n] = __builtin_amdgcn_mfma_f32_16x16x32_bf16(af[m], bfr[n], acc[m][n], 0, 0, 0);
    }

    const int rg = (lane >> 4) << 2;
#pragma unroll
    for (int m = 0; m < 4; ++m) {
#pragma unroll
        for (int n = 0; n < 2; ++n) {
            const int row0 = brow + wr + m * 16 + rg;
            const int col  = bcol + wc + n * 16 + rl;
#pragma unroll
            for (int reg = 0; reg < 4; ++reg) {
                const int row = row0 + reg;
                if (row < NN) {
                    float v = acc[m][n][reg];
                    v = v > 0.f ? v : expm1f(v);
                    out[(size_t)row * OUTF + col] = v;
                }
            }
        }
    }
}

extern "C" void kernel_launch(void* const* d_in, const int* in_sizes, int n_in,
                              void* d_out, int out_size, void* d_ws, size_t ws_size,
                              hipStream_t stream) {
    const float* h    = (const float*)d_in[0];
    // d_in[1] = adj (unused by the reference computation)
    const int*   adj1 = (const int*)d_in[2];
    const int*   adj2 = (const int*)d_in[3];
    const float* W    = (const float*)d_in[4];
    const float* a    = (const float*)d_in[5];
    const float* L_w  = (const float*)d_in[6];
    const float* L_b  = (const float*)d_in[7];
    float* out = (float*)d_out;

    float* ws = (float*)d_ws;
    const size_t PS = (size_t)NN * OUTF;            // 884736
    float* P       = ws;                            // 8 fp32 split-K slices
    float* Wa1     = P + 8 * PS;                    // 4096
    float* Wa2     = Wa1 + INF_;                    // 4096
    float* Wh1     = Wa2 + INF_;                    // 864
    float* Wh2     = Wh1 + NN;                      // 864
    float* rowpool = Wh2 + NN;                      // 2*864*54 = 93312
    float* wvec    = rowpool + 2 * NN * 54;         // 2 (pad to 4)
    unsigned int* counter = (unsigned int*)(wvec + 4);  // 1 (pad to 4)
    unsigned short* hbf    = (unsigned short*)(counter + 4);       // [896][4096]
    unsigned short* wtbf   = hbf + (size_t)896 * INF_;             // [1024][4096]
    unsigned short* Whbf_t = wtbf + (size_t)OUTF * INF_;           // [1024][864]
    unsigned short* att1bf = Whbf_t + (size_t)OUTF * NN;           // [864][864]
    unsigned short* att2bf = att1bf + (size_t)NN * NN;             // [864][864]

    prepW_kernel<<<3072, 256, 0, stream>>>(W, a, wtbf, Wa1, Wa2, counter);
    prepH_kernel<<<896, 256, 0, stream>>>(h, Wa1, Wa2, hbf, Wh1, Wh2);
    gemm1_mfma_kernel<<<dim3(8, 7, KSPLIT1), 256, 0, stream>>>(hbf, wtbf, P, INF_ / KSPLIT1);
    reduce8t_kernel<<<864, 256, 0, stream>>>(P, Whbf_t);
    attn_kernel<<<NN, 256, 0, stream>>>(Wh1, Wh2, adj1, adj2, att1bf, att2bf,
                                        rowpool, counter, L_w, L_b, wvec);
    gemm2_mfma_kernel<<<dim3(16, 7), 256, 0, stream>>>(att1bf, att2bf, wvec, Whbf_t, out);
}

// Round 14
// 199.093 us; speedup vs baseline: 1.3404x; 1.3404x over previous
//
#include <hip/hip_runtime.h>
#include <math.h>

#define NN 864
#define INF_ 4096
#define OUTF 1024
#define ALPHA 0.2f
#define NEGINF -9e15f
#define KSPLIT1 8

typedef short bf16x8 __attribute__((ext_vector_type(8)));
typedef float f32x4 __attribute__((ext_vector_type(4)));
typedef unsigned short u16x8 __attribute__((ext_vector_type(8)));
typedef unsigned short u16x4 __attribute__((ext_vector_type(4)));

__device__ __forceinline__ unsigned short f2bf(float f) {  // round-to-nearest-even
    unsigned int u = __float_as_uint(f);
    unsigned int r = (u + 0x7fffu + ((u >> 16) & 1u)) >> 16;
    return (unsigned short)r;
}
__device__ __forceinline__ float bf2f(unsigned short u) {
    return __uint_as_float((unsigned int)u << 16);
}

// ---------- block-wide reduction of two values (256 threads = 4 waves) ----------
__device__ __forceinline__ float2 blockReduce2(float v1, float v2, bool is_max) {
    __shared__ float r1[4], r2[4];
    const int lane = threadIdx.x & 63;
    const int wid  = threadIdx.x >> 6;
#pragma unroll
    for (int o = 32; o; o >>= 1) {
        float o1 = __shfl_down(v1, o, 64);
        float o2 = __shfl_down(v2, o, 64);
        if (is_max) { v1 = fmaxf(v1, o1); v2 = fmaxf(v2, o2); }
        else        { v1 += o1;           v2 += o2; }
    }
    __syncthreads();
    if (lane == 0) { r1[wid] = v1; r2[wid] = v2; }
    __syncthreads();
    float a = r1[0], b = r2[0];
#pragma unroll
    for (int w = 1; w < 4; ++w) {
        if (is_max) { a = fmaxf(a, r1[w]); b = fmaxf(b, r2[w]); }
        else        { a += r1[w];          b += r2[w]; }
    }
    return make_float2(a, b);
}

// ---------- prepW: W->W^T bf16 | Wa1/Wa2 fp32 ----------
__global__ __launch_bounds__(256) void prepW_kernel(
        const float* __restrict__ W, const float* __restrict__ a,
        unsigned short* __restrict__ wtbf, float* __restrict__ wa1,
        float* __restrict__ wa2) {
    const int b = blockIdx.x;
    if (b < 2048) {                          // W^T bf16
        const int n  = (b & 3) * 256 + threadIdx.x;
        const int k0 = (b >> 2) * 8;
        u16x8 o;
#pragma unroll
        for (int j = 0; j < 8; ++j) o[j] = f2bf(W[(size_t)(k0 + j) * OUTF + n]);
        *(u16x8*)(wtbf + (size_t)n * INF_ + k0) = o;
    } else {                                 // Wa (fp32 exact logits path), 1 k-row per wave
        const int wid  = threadIdx.x >> 6;
        const int lane = threadIdx.x & 63;
        const int k = (b - 2048) * 4 + wid;
        const float* row = W + (size_t)k * OUTF;
        float s1 = 0.f, s2 = 0.f;
#pragma unroll
        for (int f = lane * 4; f < OUTF; f += 256) {
            float4 w = *(const float4*)(row + f);
            float4 x = *(const float4*)(a + f);
            float4 y = *(const float4*)(a + OUTF + f);
            s1 += w.x * x.x + w.y * x.y + w.z * x.z + w.w * x.w;
            s2 += w.x * y.x + w.y * y.y + w.z * y.z + w.w * y.w;
        }
#pragma unroll
        for (int o = 32; o; o >>= 1) { s1 += __shfl_down(s1, o, 64); s2 += __shfl_down(s2, o, 64); }
        if (lane == 0) { wa1[k] = s1; wa2[k] = s2; }
    }
}

// ---------- prepH: h->bf16 (rows 864..895 zeroed) fused with Wh1/Wh2 dots ----------
__global__ __launch_bounds__(256) void prepH_kernel(
        const float* __restrict__ h, const float* __restrict__ wa1,
        const float* __restrict__ wa2, unsigned short* __restrict__ hbf,
        float* __restrict__ wh1, float* __restrict__ wh2) {
    const int i = blockIdx.x;
    const int f = threadIdx.x * 16;
    if (i >= NN) {                            // zero pad rows for MFMA tiles
        u16x8 z;
#pragma unroll
        for (int j = 0; j < 8; ++j) z[j] = 0;
        *(u16x8*)(hbf + (size_t)i * INF_ + f)     = z;
        *(u16x8*)(hbf + (size_t)i * INF_ + f + 8) = z;
        return;
    }
    const float* row = h + (size_t)i * INF_;
    float4 f0 = *(const float4*)(row + f);
    float4 f1 = *(const float4*)(row + f + 4);
    float4 f2 = *(const float4*)(row + f + 8);
    float4 f3 = *(const float4*)(row + f + 12);
    u16x8 o0, o1;
    o0[0] = f2bf(f0.x); o0[1] = f2bf(f0.y); o0[2] = f2bf(f0.z); o0[3] = f2bf(f0.w);
    o0[4] = f2bf(f1.x); o0[5] = f2bf(f1.y); o0[6] = f2bf(f1.z); o0[7] = f2bf(f1.w);
    o1[0] = f2bf(f2.x); o1[1] = f2bf(f2.y); o1[2] = f2bf(f2.z); o1[3] = f2bf(f2.w);
    o1[4] = f2bf(f3.x); o1[5] = f2bf(f3.y); o1[6] = f2bf(f3.z); o1[7] = f2bf(f3.w);
    *(u16x8*)(hbf + (size_t)i * INF_ + f)     = o0;
    *(u16x8*)(hbf + (size_t)i * INF_ + f + 8) = o1;
    float4 x0 = *(const float4*)(wa1 + f),     x1 = *(const float4*)(wa1 + f + 4);
    float4 x2 = *(const float4*)(wa1 + f + 8), x3 = *(const float4*)(wa1 + f + 12);
    float4 y0 = *(const float4*)(wa2 + f),     y1 = *(const float4*)(wa2 + f + 4);
    float4 y2 = *(const float4*)(wa2 + f + 8), y3 = *(const float4*)(wa2 + f + 12);
    float s1 = f0.x * x0.x + f0.y * x0.y + f0.z * x0.z + f0.w * x0.w
             + f1.x * x1.x + f1.y * x1.y + f1.z * x1.z + f1.w * x1.w
             + f2.x * x2.x + f2.y * x2.y + f2.z * x2.z + f2.w * x2.w
             + f3.x * x3.x + f3.y * x3.y + f3.z * x3.z + f3.w * x3.w;
    float s2 = f0.x * y0.x + f0.y * y0.y + f0.z * y0.z + f0.w * y0.w
             + f1.x * y1.x + f1.y * y1.y + f1.z * y1.z + f1.w * y1.w
             + f2.x * y2.x + f2.y * y2.y + f2.z * y2.z + f2.w * y2.w
             + f3.x * y3.x + f3.y * y3.y + f3.z * y3.z + f3.w * y3.w;
    float2 s = blockReduce2(s1, s2, false);
    if (threadIdx.x == 0) { wh1[i] = s.x; wh2[i] = s.y; }
}

// ---------- GEMM1 (bf16 MFMA): P[z] = hbf @ wtbf^T, 128x128 tile, BK=32 ----------
__global__ __launch_bounds__(256) void gemm1_mfma_kernel(
        const unsigned short* __restrict__ Abf,   // [896][4096]
        const unsigned short* __restrict__ Btbf,  // [1024][4096]
        float* __restrict__ P, int kchunk) {
    __shared__ unsigned short Als[128][40];
    __shared__ unsigned short Bls[128][40];
    const int tid  = threadIdx.x;
    const int lane = tid & 63;
    const int wid  = tid >> 6;
    const int wr   = (wid >> 1) * 64;
    const int wc   = (wid & 1) * 64;
    const int brow = blockIdx.y * 128;
    const int bcol = blockIdx.x * 128;
    const int k0   = blockIdx.z * kchunk;
    const int r0   = tid >> 2;
    const int kq0  = (tid & 3) << 3;

    f32x4 acc[4][4];
#pragma unroll
    for (int m = 0; m < 4; ++m)
#pragma unroll
        for (int n = 0; n < 4; ++n) acc[m][n] = (f32x4){0.f, 0.f, 0.f, 0.f};

    const unsigned short* ag = Abf  + (size_t)(brow + r0) * INF_ + kq0;
    const unsigned short* bg = Btbf + (size_t)(bcol + r0) * INF_ + kq0;
    const int rl  = lane & 15;
    const int kq2 = (lane >> 4) << 3;

    for (int kk = k0; kk < k0 + kchunk; kk += 32) {
        bf16x8 a0 = *(const bf16x8*)(ag + kk);
        bf16x8 a1 = *(const bf16x8*)(ag + (size_t)64 * INF_ + kk);
        bf16x8 b0 = *(const bf16x8*)(bg + kk);
        bf16x8 b1 = *(const bf16x8*)(bg + (size_t)64 * INF_ + kk);
        __syncthreads();
        *(bf16x8*)&Als[r0][kq0]      = a0;
        *(bf16x8*)&Als[r0 + 64][kq0] = a1;
        *(bf16x8*)&Bls[r0][kq0]      = b0;
        *(bf16x8*)&Bls[r0 + 64][kq0] = b1;
        __syncthreads();
        bf16x8 af[4], bfr[4];
#pragma unroll
        for (int m = 0; m < 4; ++m) af[m]  = *(const bf16x8*)&Als[wr + m * 16 + rl][kq2];
#pragma unroll
        for (int n = 0; n < 4; ++n) bfr[n] = *(const bf16x8*)&Bls[wc + n * 16 + rl][kq2];
#pragma unroll
        for (int m = 0; m < 4; ++m)
#pragma unroll
            for (int n = 0; n < 4; ++n)
                acc[m][n] = __builtin_amdgcn_mfma_f32_16x16x32_bf16(af[m], bfr[n], acc[m][n], 0, 0, 0);
    }

    float* Pz = P + (size_t)blockIdx.z * NN * OUTF;
    const int rg = (lane >> 4) << 2;   // C/D: col=lane&15, row=(lane>>4)*4+reg (m89)
#pragma unroll
    for (int m = 0; m < 4; ++m) {
#pragma unroll
        for (int n = 0; n < 4; ++n) {
            const int row0 = brow + wr + m * 16 + rg;
            const int col  = bcol + wc + n * 16 + rl;
#pragma unroll
            for (int reg = 0; reg < 4; ++reg) {
                const int row = row0 + reg;
                if (row < NN) Pz[(size_t)row * OUTF + col] = acc[m][n][reg];
            }
        }
    }
}

// ---------- reduce 8 split-K partials -> Wh^T bf16 [1024][864], tiled LDS transpose ----------
__global__ __launch_bounds__(256) void reduce8t_kernel(const float* __restrict__ P,
                                                       unsigned short* __restrict__ Wt) {
    __shared__ unsigned short T[32][36];     // 36-stride: 2-way banks (free)
    const size_t stride = (size_t)NN * OUTF;
    const int m0 = (blockIdx.x >> 5) * 32;   // 27 row-tiles
    const int c0 = (blockIdx.x & 31) * 32;   // 32 col-tiles
    const int r  = threadIdx.x >> 3;
    const int c4 = (threadIdx.x & 7) << 2;
    const float* base = P + (size_t)(m0 + r) * OUTF + c0 + c4;
    float4 s = *(const float4*)base;
#pragma unroll
    for (int z = 1; z < KSPLIT1; ++z) {
        float4 v = *(const float4*)(base + (size_t)z * stride);
        s.x += v.x; s.y += v.y; s.z += v.z; s.w += v.w;
    }
    T[r][c4 + 0] = f2bf(s.x); T[r][c4 + 1] = f2bf(s.y);
    T[r][c4 + 2] = f2bf(s.z); T[r][c4 + 3] = f2bf(s.w);
    __syncthreads();
    const int c  = threadIdx.x >> 3;
    const int m8 = (threadIdx.x & 7) << 2;
    u16x4 o;
#pragma unroll
    for (int j = 0; j < 4; ++j) o[j] = T[m8 + j][c];
    *(u16x4*)(Wt + (size_t)(c0 + c) * NN + m0 + m8) = o;
}

// ---------- attn: masked softmaxes -> att bf16 + 16-col pool partials ----------
__global__ __launch_bounds__(256) void attn_kernel(
        const float* __restrict__ Wh1, const float* __restrict__ Wh2,
        const int* __restrict__ adj1, const int* __restrict__ adj2,
        unsigned short* __restrict__ att1, unsigned short* __restrict__ att2,
        float* __restrict__ rowpool) {
    const int i = blockIdx.x, t = threadIdx.x;
    const int c = t * 4;
    const bool valid = c < NN;               // t < 216
    const float wh1i = Wh1[i];
    float l1[4], l2[4];
    float m1 = NEGINF, m2 = NEGINF;
    if (valid) {
        int4   av1 = *(const int4*)(adj1 + (size_t)i * NN + c);
        int4   av2 = *(const int4*)(adj2 + (size_t)i * NN + c);
        float4 w2  = *(const float4*)(Wh2 + c);
        float e;
        e = wh1i + w2.x; e = e > 0.f ? e : ALPHA * e;
        l1[0] = av1.x > 0 ? e : NEGINF; l2[0] = av2.x > 0 ? e : NEGINF;
        e = wh1i + w2.y; e = e > 0.f ? e : ALPHA * e;
        l1[1] = av1.y > 0 ? e : NEGINF; l2[1] = av2.y > 0 ? e : NEGINF;
        e = wh1i + w2.z; e = e > 0.f ? e : ALPHA * e;
        l1[2] = av1.z > 0 ? e : NEGINF; l2[2] = av2.z > 0 ? e : NEGINF;
        e = wh1i + w2.w; e = e > 0.f ? e : ALPHA * e;
        l1[3] = av1.w > 0 ? e : NEGINF; l2[3] = av2.w > 0 ? e : NEGINF;
#pragma unroll
        for (int j = 0; j < 4; ++j) { m1 = fmaxf(m1, l1[j]); m2 = fmaxf(m2, l2[j]); }
    } else {
#pragma unroll
        for (int j = 0; j < 4; ++j) { l1[j] = NEGINF; l2[j] = NEGINF; }
    }
    float2 m = blockReduce2(m1, m2, true);
    float x1[4], x2[4], s1 = 0.f, s2 = 0.f;
#pragma unroll
    for (int j = 0; j < 4; ++j) {
        x1[j] = valid ? expf(l1[j] - m.x) : 0.f;   // invalid lanes excluded from sum
        x2[j] = valid ? expf(l2[j] - m.y) : 0.f;
        s1 += x1[j]; s2 += x2[j];
    }
    float2 s = blockReduce2(s1, s2, false);
    const float inv1 = 1.f / s.x, inv2 = 1.f / s.y;
    float a1[4], a2[4];
    if (valid) {
        u16x4 o1, o2;
#pragma unroll
        for (int j = 0; j < 4; ++j) {
            a1[j] = x1[j] * inv1; o1[j] = f2bf(a1[j]);
            a2[j] = x2[j] * inv2; o2[j] = f2bf(a2[j]);
        }
        *(u16x4*)(att1 + (size_t)i * NN + c) = o1;
        *(u16x4*)(att2 + (size_t)i * NN + c) = o2;
    } else {
#pragma unroll
        for (int j = 0; j < 4; ++j) { a1[j] = NEGINF; a2[j] = NEGINF; }
    }
    float p1 = fmaxf(fmaxf(a1[0], a1[1]), fmaxf(a1[2], a1[3]));
    float p2 = fmaxf(fmaxf(a2[0], a2[1]), fmaxf(a2[2], a2[3]));
    p1 = fmaxf(p1, __shfl_xor(p1, 1, 64)); p1 = fmaxf(p1, __shfl_xor(p1, 2, 64));
    p2 = fmaxf(p2, __shfl_xor(p2, 1, 64)); p2 = fmaxf(p2, __shfl_xor(p2, 2, 64));
    if ((t & 3) == 0 && valid) {
        rowpool[(size_t)i * 54 + (t >> 2)] = p1;
        rowpool[(size_t)NN * 54 + (size_t)i * 54 + (t >> 2)] = p2;
    }
}

// ---------- finish pool over 16 rows + linear + leaky + softmax -> wvec (1 block) ----------
__global__ __launch_bounds__(1024) void poolw_kernel(const float* __restrict__ rowpool,
                                                     const float* __restrict__ L_w,
                                                     const float* __restrict__ L_b,
                                                     float* __restrict__ wvec) {
    __shared__ float r1[16], r2[16];
    const int t = threadIdx.x;
    float p0 = 0.f, p1 = 0.f;
    for (int p = t; p < 2916; p += 1024) {
        const int pi = p / 54, pj = p - pi * 54;
        const float* rp0 = rowpool + (size_t)(pi * 16) * 54 + pj;
        const float* rp1 = rp0 + (size_t)NN * 54;
        float mx0 = NEGINF, mx1 = NEGINF;
#pragma unroll
        for (int r = 0; r < 16; ++r) {
            mx0 = fmaxf(mx0, rp0[r * 54]);
            mx1 = fmaxf(mx1, rp1[r * 54]);
        }
        const float lw = L_w[p];
        p0 += mx0 * lw; p1 += mx1 * lw;
    }
#pragma unroll
    for (int o = 32; o; o >>= 1) { p0 += __shfl_down(p0, o, 64); p1 += __shfl_down(p1, o, 64); }
    if ((t & 63) == 0) { r1[t >> 6] = p0; r2[t >> 6] = p1; }
    __syncthreads();
    if (t == 0) {
        float s0 = 0.f, s1 = 0.f;
#pragma unroll
        for (int w = 0; w < 16; ++w) { s0 += r1[w]; s1 += r2[w]; }
        float l0 = s0 + L_b[0]; l0 = l0 > 0.f ? l0 : ALPHA * l0;
        float l1 = s1 + L_b[0]; l1 = l1 > 0.f ? l1 : ALPHA * l1;
        const float mx = fmaxf(l0, l1);
        const float e0 = expf(l0 - mx), e1 = expf(l1 - mx);
        const float inv = 1.f / (e0 + e1);
        wvec[0] = e0 * inv; wvec[1] = e1 * inv;
    }
}

// ---------- GEMM2 (bf16 MFMA, single-K): out = ELU((w0*att1+w1*att2) @ Wh) ----------
__global__ __launch_bounds__(256) void gemm2_mfma_kernel(
        const unsigned short* __restrict__ A1, const unsigned short* __restrict__ A2,
        const float* __restrict__ wvec, const unsigned short* __restrict__ Bt,  // [1024][864]
        float* __restrict__ out) {
    __shared__ unsigned short Als[128][40];
    __shared__ unsigned short Bls[64][40];
    const int tid  = threadIdx.x;
    const int lane = tid & 63;
    const int wid  = tid >> 6;
    const int wr   = (wid >> 1) * 64;        // 2x2 waves of 64x32
    const int wc   = (wid & 1) * 32;
    const int brow = blockIdx.y * 128;
    const int bcol = blockIdx.x * 64;
    const int r0   = tid >> 2;
    const int kq0  = (tid & 3) << 3;
    const float w0 = wvec[0], w1 = wvec[1];

    f32x4 acc[4][2];
#pragma unroll
    for (int m = 0; m < 4; ++m)
#pragma unroll
        for (int n = 0; n < 2; ++n) acc[m][n] = (f32x4){0.f, 0.f, 0.f, 0.f};

    const int rl  = lane & 15;
    const int kq2 = (lane >> 4) << 3;

    for (int kk = 0; kk < NN; kk += 32) {    // 27 iters
        u16x8 av[2];
#pragma unroll
        for (int half = 0; half < 2; ++half) {
            const int grow = brow + r0 + half * 64;
            u16x8 o;
            if (grow < NN) {
                u16x8 v1 = *(const u16x8*)(A1 + (size_t)grow * NN + kk + kq0);
                u16x8 v2 = *(const u16x8*)(A2 + (size_t)grow * NN + kk + kq0);
#pragma unroll
                for (int j = 0; j < 8; ++j)
                    o[j] = f2bf(w0 * bf2f(v1[j]) + w1 * bf2f(v2[j]));
            } else {
#pragma unroll
                for (int j = 0; j < 8; ++j) o[j] = 0;
            }
            av[half] = o;
        }
        u16x8 bv = *(const u16x8*)(Bt + (size_t)(bcol + r0) * NN + kk + kq0);
        __syncthreads();
        *(u16x8*)&Als[r0][kq0]      = av[0];
        *(u16x8*)&Als[r0 + 64][kq0] = av[1];
        *(u16x8*)&Bls[r0][kq0]      = bv;
        __syncthreads();
        bf16x8 af[4], bfr[2];
#pragma unroll
        for (int m = 0; m < 4; ++m) af[m]  = *(const bf16x8*)&Als[wr + m * 16 + rl][kq2];
#pragma unroll
        for (int n = 0; n < 2; ++n) bfr[n] = *(const bf16x8*)&Bls[wc + n * 16 + rl][kq2];
#pragma unroll
        for (int m = 0; m < 4; ++m)
#pragma unroll
            for (int n = 0; n < 2; ++n)
                acc[m][n] = __builtin_amdgcn_mfma_f32_16x16x32_bf16(af[m], bfr[n], acc[m][n], 0, 0, 0);
    }

    const int rg = (lane >> 4) << 2;
#pragma unroll
    for (int m = 0; m < 4; ++m) {
#pragma unroll
        for (int n = 0; n < 2; ++n) {
            const int row0 = brow + wr + m * 16 + rg;
            const int col  = bcol + wc + n * 16 + rl;
#pragma unroll
            for (int reg = 0; reg < 4; ++reg) {
                const int row = row0 + reg;
                if (row < NN) {
                    float v = acc[m][n][reg];
                    v = v > 0.f ? v : expm1f(v);
                    out[(size_t)row * OUTF + col] = v;
                }
            }
        }
    }
}

extern "C" void kernel_launch(void* const* d_in, const int* in_sizes, int n_in,
                              void* d_out, int out_size, void* d_ws, size_t ws_size,
                              hipStream_t stream) {
    const float* h    = (const float*)d_in[0];
    // d_in[1] = adj (unused by the reference computation)
    const int*   adj1 = (const int*)d_in[2];
    const int*   adj2 = (const int*)d_in[3];
    const float* W    = (const float*)d_in[4];
    const float* a    = (const float*)d_in[5];
    const float* L_w  = (const float*)d_in[6];
    const float* L_b  = (const float*)d_in[7];
    float* out = (float*)d_out;

    float* ws = (float*)d_ws;
    const size_t PS = (size_t)NN * OUTF;            // 884736
    float* P       = ws;                            // 8 fp32 split-K slices
    float* Wa1     = P + 8 * PS;                    // 4096
    float* Wa2     = Wa1 + INF_;                    // 4096
    float* Wh1     = Wa2 + INF_;                    // 864
    float* Wh2     = Wh1 + NN;                      // 864
    float* rowpool = Wh2 + NN;                      // 2*864*54 = 93312
    float* wvec    = rowpool + 2 * NN * 54;         // 2 (pad to 8)
    unsigned short* hbf    = (unsigned short*)(wvec + 8);          // [896][4096]
    unsigned short* wtbf   = hbf + (size_t)896 * INF_;             // [1024][4096]
    unsigned short* Whbf_t = wtbf + (size_t)OUTF * INF_;           // [1024][864]
    unsigned short* att1bf = Whbf_t + (size_t)OUTF * NN;           // [864][864]
    unsigned short* att2bf = att1bf + (size_t)NN * NN;             // [864][864]

    prepW_kernel<<<3072, 256, 0, stream>>>(W, a, wtbf, Wa1, Wa2);
    prepH_kernel<<<896, 256, 0, stream>>>(h, Wa1, Wa2, hbf, Wh1, Wh2);
    gemm1_mfma_kernel<<<dim3(8, 7, KSPLIT1), 256, 0, stream>>>(hbf, wtbf, P, INF_ / KSPLIT1);
    reduce8t_kernel<<<864, 256, 0, stream>>>(P, Whbf_t);
    attn_kernel<<<NN, 256, 0, stream>>>(Wh1, Wh2, adj1, adj2, att1bf, att2bf, rowpool);
    poolw_kernel<<<1, 1024, 0, stream>>>(rowpool, L_w, L_b, wvec);
    gemm2_mfma_kernel<<<dim3(16, 7), 256, 0, stream>>>(att1bf, att2bf, wvec, Whbf_t, out);
}